// Round 1
// baseline (882.511 us; speedup 1.0000x reference)
//
#include <hip/hip_runtime.h>
#include <stdint.h>

#define T_TOK 65536
#define H_DIM 768
#define N_SUP 32768
#define Q_QRY 32768
#define C_CLS 10
#define K_DIM 2304   // 3*H
#define M_TOT 65536  // N+Q

typedef __bf16 bf16x8 __attribute__((ext_vector_type(8)));
typedef float f32x4 __attribute__((ext_vector_type(4)));

typedef __attribute__((address_space(3))) void lds_void;
typedef const __attribute__((address_space(1))) void g_void;

__device__ __forceinline__ ushort f2bf(float f) {
  union { float f; uint32_t u; } v; v.f = f;
  uint32_t r = (v.u + 0x7FFFu + ((v.u >> 16) & 1u)) >> 16;
  return (ushort)r;
}
__device__ __forceinline__ float bf2f(ushort h) {
  union { uint32_t u; float f; } v; v.u = ((uint32_t)h) << 16; return v.f;
}

// ---------------- W^T + bf16 convert: Wt[n][k] = W[k][n] ----------------
__global__ void wt_kernel(const float* __restrict__ W, ushort* __restrict__ Wt) {
  int idx = blockIdx.x * 256 + threadIdx.x;
  if (idx >= H_DIM * K_DIM) return;
  int n = idx / K_DIM, k = idx - n * K_DIM;
  Wt[idx] = f2bf(W[(size_t)k * H_DIM + n]);
}

// ---------------- feature build: one wave per span ----------------
// feat[i] = [ te[s], te[e-1], mean(te[s:e]) ]  (bf16, 2304 per row)
__global__ void feat_build(const float* __restrict__ te, const int* __restrict__ spS,
                           const int* __restrict__ spQ, ushort* __restrict__ feat) {
  int wid = (int)(((size_t)blockIdx.x * blockDim.x + threadIdx.x) >> 6);
  int lane = threadIdx.x & 63;
  if (wid >= M_TOT) return;
  int s, e;
  if (wid < N_SUP) { s = spS[2 * wid]; e = spS[2 * wid + 1]; }
  else             { int w = wid - N_SUP; s = spQ[2 * w]; e = spQ[2 * w + 1]; }
  int len = e - s;

  const float4* rp = (const float4*)(te + (size_t)s * H_DIM);
  float4 first[3], sum[3], last[3];
#pragma unroll
  for (int j = 0; j < 3; ++j) { float4 v = rp[lane + 64 * j]; first[j] = v; sum[j] = v; }
  for (int r = 1; r < len; ++r) {
    const float4* p = (const float4*)(te + (size_t)(s + r) * H_DIM);
#pragma unroll
    for (int j = 0; j < 3; ++j) {
      float4 v = p[lane + 64 * j];
      sum[j].x += v.x; sum[j].y += v.y; sum[j].z += v.z; sum[j].w += v.w;
    }
  }
  const float4* lp = (const float4*)(te + (size_t)(e - 1) * H_DIM);
#pragma unroll
  for (int j = 0; j < 3; ++j) last[j] = lp[lane + 64 * j];

  float inv = 1.0f / (float)len;
  ushort* fr = feat + (size_t)wid * K_DIM;
#pragma unroll
  for (int j = 0; j < 3; ++j) {
    int c4 = (lane + 64 * j) * 4;
    ushort4 a, b, c;
    a.x = f2bf(first[j].x); a.y = f2bf(first[j].y); a.z = f2bf(first[j].z); a.w = f2bf(first[j].w);
    b.x = f2bf(last[j].x);  b.y = f2bf(last[j].y);  b.z = f2bf(last[j].z);  b.w = f2bf(last[j].w);
    c.x = f2bf(sum[j].x * inv); c.y = f2bf(sum[j].y * inv);
    c.z = f2bf(sum[j].z * inv); c.w = f2bf(sum[j].w * inv);
    *(ushort4*)(fr + c4) = a;
    *(ushort4*)(fr + H_DIM + c4) = b;
    *(ushort4*)(fr + 2 * H_DIM + c4) = c;
  }
}

// ---------------- GEMM (feat @ W) + bias + exact GELU -> emb (bf16) ----------------
// A: M_TOT x K_DIM bf16 row-major; Bt: H_DIM x K_DIM bf16 row-major (= W^T)
// 128x128 tile, BK=64, 256 threads (4 waves, 2x2), mfma 16x16x32 bf16.
__global__ __launch_bounds__(256) void gemm_gelu(const ushort* __restrict__ A,
                                                 const ushort* __restrict__ Bt,
                                                 const float* __restrict__ bias,
                                                 ushort* __restrict__ emb) {
  __shared__ ushort As[128 * 64];
  __shared__ ushort Bs[128 * 64];

  // bijective XCD swizzle: nwg = 3072, q = 384, r = 0
  int orig = blockIdx.x;
  int wg = (orig & 7) * 384 + (orig >> 3);
  int rowT = wg / 6, colT = wg - rowT * 6;
  int m0 = rowT * 128, n0 = colT * 128;

  int tid = threadIdx.x, lane = tid & 63, wave = tid >> 6;
  int wr = wave >> 1, wc = wave & 1;      // 2x2 wave grid, each wave 64x64
  int l15 = lane & 15, l4 = lane >> 4;

  f32x4 acc[4][4];
#pragma unroll
  for (int i = 0; i < 4; ++i)
#pragma unroll
    for (int j = 0; j < 4; ++j) acc[i][j] = (f32x4){0.f, 0.f, 0.f, 0.f};

  for (int k0 = 0; k0 < K_DIM; k0 += 64) {
#pragma unroll
    for (int j = 0; j < 4; ++j) {
      int o = j * 4096 + wave * 1024 + lane * 16;  // byte offset in 16KB tile
      int r = o >> 7;                               // row (128B per row)
      int c = (o & 127) >> 1;                       // bf16 col within row
      const ushort* ga = A + ((size_t)(m0 + r) * K_DIM + k0 + c);
      __builtin_amdgcn_global_load_lds((g_void*)ga,
          (lds_void*)((char*)As + j * 4096 + wave * 1024), 16, 0, 0);
      const ushort* gb = Bt + ((size_t)(n0 + r) * K_DIM + k0 + c);
      __builtin_amdgcn_global_load_lds((g_void*)gb,
          (lds_void*)((char*)Bs + j * 4096 + wave * 1024), 16, 0, 0);
    }
    __syncthreads();
#pragma unroll
    for (int kk = 0; kk < 2; ++kk) {
      bf16x8 a[4], b[4];
#pragma unroll
      for (int m = 0; m < 4; ++m)
        a[m] = *reinterpret_cast<const bf16x8*>(&As[(wr * 64 + m * 16 + l15) * 64 + kk * 32 + l4 * 8]);
#pragma unroll
      for (int n = 0; n < 4; ++n)
        b[n] = *reinterpret_cast<const bf16x8*>(&Bs[(wc * 64 + n * 16 + l15) * 64 + kk * 32 + l4 * 8]);
#pragma unroll
      for (int m = 0; m < 4; ++m)
#pragma unroll
        for (int n = 0; n < 4; ++n)
          acc[m][n] = __builtin_amdgcn_mfma_f32_16x16x32_bf16(a[m], b[n], acc[m][n], 0, 0, 0);
    }
    __syncthreads();
  }

  // epilogue: bias + exact gelu, store bf16
#pragma unroll
  for (int m = 0; m < 4; ++m) {
#pragma unroll
    for (int n = 0; n < 4; ++n) {
      int col = n0 + wc * 64 + n * 16 + l15;
      float bc = bias[col];
#pragma unroll
      for (int v = 0; v < 4; ++v) {
        int row = m0 + wr * 64 + m * 16 + l4 * 4 + v;
        float x = acc[m][n][v] + bc;
        float g = 0.5f * x * (1.0f + erff(x * 0.70710678118654752f));
        emb[(size_t)row * H_DIM + col] = f2bf(g);
      }
    }
  }
}

// ---------------- proto accumulation: LDS-local segment sums + atomics ----------------
__global__ void proto_accum(const ushort* __restrict__ supEmb, const int* __restrict__ labels,
                            float* __restrict__ pSum, float* __restrict__ pCnt) {
  __shared__ float ls[C_CLS * H_DIM];
  __shared__ int lc[C_CLS];
  int t = threadIdx.x;
  for (int i = t; i < C_CLS * H_DIM; i += 256) ls[i] = 0.f;
  if (t < C_CLS) lc[t] = 0;
  __syncthreads();
  int base = blockIdx.x * 128;
  for (int si = 0; si < 128; ++si) {
    int sp = base + si;
    int lab = labels[sp];
    const ushort* er = supEmb + (size_t)sp * H_DIM;
#pragma unroll
    for (int j = 0; j < 3; ++j) {
      int c = t + j * 256;
      ls[lab * H_DIM + c] += bf2f(er[c]);
    }
    if (t == 0) lc[lab]++;
  }
  __syncthreads();
  for (int i = t; i < C_CLS * H_DIM; i += 256) atomicAdd(&pSum[i], ls[i]);
  if (t < C_CLS) atomicAdd(&pCnt[t], (float)lc[t]);
}

// ---------------- proto normalize (1 block) ----------------
__global__ void proto_norm(const float* __restrict__ pSum, const float* __restrict__ pCnt,
                           float* __restrict__ pN) {
  __shared__ float red[4];
  int t = threadIdx.x, lane = t & 63, wave = t >> 6;
  for (int c = 0; c < C_CLS; ++c) {
    float cnt = pCnt[c];
    float x[3];
#pragma unroll
    for (int j = 0; j < 3; ++j) {
      int h = t + j * 256;
      float v;
      if (cnt > 0.5f) v = pSum[c * H_DIM + h] / cnt;
      else {
        float gs = 0.f;
        for (int cc = 0; cc < C_CLS; ++cc) gs += pSum[cc * H_DIM + h];
        v = gs / (float)N_SUP;
      }
      x[j] = v;
    }
    float ss = x[0] * x[0] + x[1] * x[1] + x[2] * x[2];
#pragma unroll
    for (int o = 32; o; o >>= 1) ss += __shfl_xor(ss, o);
    if (lane == 0) red[wave] = ss;
    __syncthreads();
    float tot = red[0] + red[1] + red[2] + red[3];
    float inv = 1.0f / fmaxf(sqrtf(tot), 1e-12f);
#pragma unroll
    for (int j = 0; j < 3; ++j) pN[c * H_DIM + t + j * 256] = x[j] * inv;
    __syncthreads();
  }
}

// ---------------- query sim: one wave per query row ----------------
__global__ void sim_kernel(const ushort* __restrict__ emb, const float* __restrict__ pN,
                           float* __restrict__ out) {
  __shared__ float lp[C_CLS * H_DIM];
  int t = threadIdx.x;
  for (int i = t; i < C_CLS * H_DIM; i += 256) lp[i] = pN[i];
  __syncthreads();
  int lane = t & 63, wave = t >> 6;
  for (int row = blockIdx.x * 4 + wave; row < Q_QRY; row += gridDim.x * 4) {
    const ushort* qr = emb + (size_t)(N_SUP + row) * H_DIM;
    float dot[C_CLS] = {0, 0, 0, 0, 0, 0, 0, 0, 0, 0};
    float sq = 0.f;
#pragma unroll
    for (int j = 0; j < 12; ++j) {
      float v = bf2f(qr[lane + 64 * j]);
      sq += v * v;
#pragma unroll
      for (int p = 0; p < C_CLS; ++p) dot[p] += v * lp[p * H_DIM + lane + 64 * j];
    }
#pragma unroll
    for (int o = 32; o; o >>= 1) {
      sq += __shfl_xor(sq, o);
#pragma unroll
      for (int p = 0; p < C_CLS; ++p) dot[p] += __shfl_xor(dot[p], o);
    }
    if (lane == 0) {
      float inv = 1.0f / fmaxf(sqrtf(sq), 1e-12f);
      float* o = out + (size_t)row * (C_CLS + 1);
      o[0] = dot[0] * inv; o[1] = dot[1] * inv; o[2] = dot[2] * inv;
      o[3] = dot[3] * inv; o[4] = dot[4] * inv; o[5] = dot[5] * inv;
      o[6] = dot[6] * inv; o[7] = dot[7] * inv; o[8] = dot[8] * inv;
      o[9] = dot[9] * inv; o[10] = 0.5f;
    }
  }
}

extern "C" void kernel_launch(void* const* d_in, const int* in_sizes, int n_in,
                              void* d_out, int out_size, void* d_ws, size_t ws_size,
                              hipStream_t stream) {
  const float* token_emb = (const float*)d_in[0];
  const int*   spansS    = (const int*)d_in[1];
  const int*   labels    = (const int*)d_in[2];
  const int*   spansQ    = (const int*)d_in[3];
  const float* W         = (const float*)d_in[4];
  const float* b         = (const float*)d_in[5];
  float* out = (float*)d_out;

  char* ws = (char*)d_ws;
  size_t featB = (size_t)M_TOT * K_DIM * 2;   // 301,989,888
  size_t embB  = (size_t)M_TOT * H_DIM * 2;   // 100,663,296
  size_t wtB   = (size_t)H_DIM * K_DIM * 2;   //   3,538,944
  ushort* feat = (ushort*)ws;
  ushort* emb  = (ushort*)(ws + featB);
  ushort* Wt   = (ushort*)(ws + featB + embB);
  float*  pSum = (float*)(ws + featB + embB + wtB);
  float*  pCnt = pSum + C_CLS * H_DIM;
  float*  pN   = pCnt + 64;

  hipMemsetAsync(pSum, 0, (C_CLS * H_DIM + 64) * sizeof(float), stream);
  wt_kernel<<<(H_DIM * K_DIM + 255) / 256, 256, 0, stream>>>(W, Wt);
  feat_build<<<M_TOT / 4, 256, 0, stream>>>(token_emb, spansS, spansQ, feat);
  gemm_gelu<<<512 * 6, 256, 0, stream>>>(feat, Wt, b, emb);
  proto_accum<<<N_SUP / 128, 256, 0, stream>>>(emb, labels, pSum, pCnt);
  proto_norm<<<1, 256, 0, stream>>>(pSum, pCnt, pN);
  sim_kernel<<<512, 256, 0, stream>>>(emb, pN, out);
}

// Round 2
// 630.075 us; speedup vs baseline: 1.4006x; 1.4006x over previous
//
#include <hip/hip_runtime.h>
#include <stdint.h>

#define H_DIM 768
#define N_SUP 32768
#define Q_QRY 32768
#define C_CLS 10
#define M_TOT 65536   // N+Q spans; also = token count T
#define KG 768        // GEMM K
#define NG 2304       // GEMM N (=3*H)
#define NT 12         // K tiles of 64

typedef __bf16 bf16x8 __attribute__((ext_vector_type(8)));
typedef float f32x4 __attribute__((ext_vector_type(4)));
typedef __attribute__((address_space(3))) void lds_void;
typedef const __attribute__((address_space(1))) void g_void;

__device__ __forceinline__ ushort f2bf(float f) {
  union { float f; uint32_t u; } v; v.f = f;
  uint32_t r = (v.u + 0x7FFFu + ((v.u >> 16) & 1u)) >> 16;
  return (ushort)r;
}
__device__ __forceinline__ float bf2f(ushort h) {
  union { uint32_t u; float f; } v; v.u = ((uint32_t)h) << 16; return v.f;
}
__device__ __forceinline__ float gelu_f(float x) {
  return 0.5f * x * (1.0f + erff(x * 0.70710678118654752f));
}

// ---------------- token_emb fp32 -> bf16 ----------------
__global__ void cvt_kernel(const float* __restrict__ te, ushort* __restrict__ tb) {
  size_t i = (((size_t)blockIdx.x * 256) + threadIdx.x) * 8;
  float4 v0 = *(const float4*)(te + i);
  float4 v1 = *(const float4*)(te + i + 4);
  ushort4 o0, o1;
  o0.x = f2bf(v0.x); o0.y = f2bf(v0.y); o0.z = f2bf(v0.z); o0.w = f2bf(v0.w);
  o1.x = f2bf(v1.x); o1.y = f2bf(v1.y); o1.z = f2bf(v1.z); o1.w = f2bf(v1.w);
  *(ushort4*)(tb + i) = o0;
  *(ushort4*)(tb + i + 4) = o1;
}

// ---------------- Bt[n][k] = Wall^T : Bt[j][k] = W[(j/768)*768 + k][j%768] ----------------
__global__ void wt2_kernel(const float* __restrict__ W, ushort* __restrict__ Bt) {
  int idx = blockIdx.x * 256 + threadIdx.x;   // < 2304*768
  int n = idx / KG, k = idx - n * KG;
  int blk = n / H_DIM;
  int c = n - blk * H_DIM;
  Bt[idx] = f2bf(W[(size_t)(blk * H_DIM + k) * H_DIM + c]);
}

// ---------------- 256x256 8-wave phase-pipelined GEMM: PQR = te_bf @ Wall ----------------
// A: 65536 x 768 bf16 row-major; Bt: 2304 x 768 bf16 row-major; C: 65536 x 2304 bf16.
// LDS slots: A[kh][db], B[kh][db], each 256 rows x 32 k = 16 KB; 8 slots = 128 KB.
// XOR swizzle: within-slot 16B slot' = slot ^ ((row>>1)&3)  (applied on BOTH global src and ds_read).
__global__ __launch_bounds__(512, 2) void gemm8(const ushort* __restrict__ A,
                                                const ushort* __restrict__ Bt,
                                                ushort* __restrict__ C) {
  __shared__ ushort lds[65536];  // 128 KB
  char* ldsc = (char*)lds;

  int orig = blockIdx.x;
  int wg = (orig & 7) * 288 + (orig >> 3);   // nwg=2304 = 8*288, bijective XCD swizzle
  int rowT = wg / 9, colT = wg - rowT * 9;
  int m0 = rowT * 256, n0 = colT * 256;

  int tid = threadIdx.x;
  int lane = tid & 63, wave = tid >> 6;
  int wr = wave >> 2, wc = wave & 3;         // 2x4 wave grid; per-wave C = 128x64
  int l15 = lane & 15, l4 = lane >> 4;

  // staging source precompute (linear LDS dest, inverse-swizzled global src)
  int row0 = tid >> 2;                        // 0..127  (L=0); L=1 adds 128
  int ss = (tid & 3) ^ ((row0 >> 1) & 3);     // same for L=1 (row+128 keeps (row>>1)&3)
  size_t eA0 = (size_t)(m0 + row0) * KG + ss * 8;
  size_t eA1 = (size_t)(m0 + row0 + 128) * KG + ss * 8;
  size_t eB0 = (size_t)(n0 + row0) * KG + ss * 8;
  size_t eB1 = (size_t)(n0 + row0 + 128) * KG + ss * 8;

  // ds_read byte offsets within a 16 KB slot (constant per thread)
  int aoff[8], boff[4];
#pragma unroll
  for (int m = 0; m < 8; ++m) {
    int r = wr * 128 + m * 16 + l15;
    aoff[m] = r * 64 + ((l4 ^ ((r >> 1) & 3)) << 4);
  }
#pragma unroll
  for (int n = 0; n < 4; ++n) {
    int r = wc * 64 + n * 16 + l15;
    boff[n] = r * 64 + ((l4 ^ ((r >> 1) & 3)) << 4);
  }

  f32x4 acc[8][4];
#pragma unroll
  for (int m = 0; m < 8; ++m)
#pragma unroll
    for (int n = 0; n < 4; ++n) acc[m][n] = (f32x4){0.f, 0.f, 0.f, 0.f};

#define SLOT_A(kh, db) (ldsc + ((kh) * 2 + (db)) * 16384)
#define SLOT_B(kh, db) (ldsc + 65536 + ((kh) * 2 + (db)) * 16384)
#define STAGE_A(tk, kh, db) do { \
    char* _d = SLOT_A(kh, db) + wave * 1024; \
    size_t _k = (size_t)(tk) * 64 + (kh) * 32; \
    __builtin_amdgcn_global_load_lds((g_void*)(A + eA0 + _k), (lds_void*)_d, 16, 0, 0); \
    __builtin_amdgcn_global_load_lds((g_void*)(A + eA1 + _k), (lds_void*)(_d + 8192), 16, 0, 0); \
  } while (0)
#define STAGE_B(tk, kh, db) do { \
    char* _d = SLOT_B(kh, db) + wave * 1024; \
    size_t _k = (size_t)(tk) * 64 + (kh) * 32; \
    __builtin_amdgcn_global_load_lds((g_void*)(Bt + eB0 + _k), (lds_void*)_d, 16, 0, 0); \
    __builtin_amdgcn_global_load_lds((g_void*)(Bt + eB1 + _k), (lds_void*)(_d + 8192), 16, 0, 0); \
  } while (0)
#define LDA4(base, o) do { _Pragma("unroll") for (int m = 0; m < 4; ++m) \
    af[m] = *reinterpret_cast<const bf16x8*>((base) + aoff[(o) + m]); } while (0)
#define LDB4(base) do { _Pragma("unroll") for (int n = 0; n < 4; ++n) \
    bf[n] = *reinterpret_cast<const bf16x8*>((base) + boff[n]); } while (0)
#define MFMA_BLOCK(MB) do { _Pragma("unroll") for (int m = 0; m < 4; ++m) \
  _Pragma("unroll") for (int n = 0; n < 4; ++n) \
    acc[(MB) + m][n] = __builtin_amdgcn_mfma_f32_16x16x32_bf16(af[m], bf[n], acc[(MB) + m][n], 0, 0, 0); \
  } while (0)
#define BARX() __builtin_amdgcn_s_barrier()
#define LGKM0() asm volatile("s_waitcnt lgkmcnt(0)" ::: "memory")
#define VM8() asm volatile("s_waitcnt vmcnt(8)" ::: "memory")

  // prologue: tile0 both halves + tile1 kh0; after vmcnt(8): tile0-kh0 landed,
  // in flight = {A1(0),B1(0),A0(1),B0(1)} — the steady-state invariant.
  STAGE_A(0, 0, 0); STAGE_B(0, 0, 0);
  STAGE_A(0, 1, 0); STAGE_B(0, 1, 0);
  STAGE_A(1, 0, 1); STAGE_B(1, 0, 1);
  VM8();
  BARX();

  bf16x8 af[4], bf[4];
  for (int t = 0; t < NT; ++t) {
    int d = t & 1, nd = d ^ 1;
    int tk1 = (t + 1 < NT) ? t + 1 : NT - 1;   // clamped targets write never-read slots
    int tk2 = (t + 2 < NT) ? t + 2 : NT - 1;
    const char* Ak0 = SLOT_A(0, d); const char* Bk0 = SLOT_B(0, d);
    const char* Ak1 = SLOT_A(1, d); const char* Bk1 = SLOT_B(1, d);
    // P1: kk0, m0-3
    LDA4(Ak0, 0); LDB4(Bk0);
    STAGE_A(tk1, 1, nd);
    BARX(); LGKM0();
    __builtin_amdgcn_s_setprio(1); MFMA_BLOCK(0); __builtin_amdgcn_s_setprio(0);
    BARX();
    // P2: kk0, m4-7 (reuse bf)
    LDA4(Ak0, 4);
    STAGE_B(tk1, 1, nd);
    BARX(); LGKM0();
    __builtin_amdgcn_s_setprio(1); MFMA_BLOCK(4); __builtin_amdgcn_s_setprio(0);
    VM8(); BARX();
    // P3: kk1, m0-3
    LDA4(Ak1, 0); LDB4(Bk1);
    STAGE_A(tk2, 0, d);
    BARX(); LGKM0();
    __builtin_amdgcn_s_setprio(1); MFMA_BLOCK(0); __builtin_amdgcn_s_setprio(0);
    BARX();
    // P4: kk1, m4-7
    LDA4(Ak1, 4);
    STAGE_B(tk2, 0, d);
    BARX(); LGKM0();
    __builtin_amdgcn_s_setprio(1); MFMA_BLOCK(4); __builtin_amdgcn_s_setprio(0);
    VM8(); BARX();
  }
  asm volatile("s_waitcnt vmcnt(0)" ::: "memory");

  // epilogue: raw bf16 C store (bias+GELU applied in combine)
#pragma unroll
  for (int m = 0; m < 8; ++m)
#pragma unroll
    for (int n = 0; n < 4; ++n) {
      int col = n0 + wc * 64 + n * 16 + l15;
      size_t rb = (size_t)(m0 + wr * 128 + m * 16 + l4 * 4) * NG + col;
#pragma unroll
      for (int v = 0; v < 4; ++v)
        C[rb + (size_t)v * NG] = f2bf(acc[m][n][v]);
    }
#undef SLOT_A
#undef SLOT_B
#undef STAGE_A
#undef STAGE_B
#undef LDA4
#undef LDB4
#undef MFMA_BLOCK
}

// ---------------- span combine: emb[i] = gelu(P[s] + Q[e-1] + mean R[s:e] + b) ----------------
__global__ void combine_kernel(const ushort* __restrict__ PQR, const int* __restrict__ spS,
                               const int* __restrict__ spQ, const float* __restrict__ bias,
                               ushort* __restrict__ emb) {
  int wid = (int)((((size_t)blockIdx.x * blockDim.x) + threadIdx.x) >> 6);
  int lane = threadIdx.x & 63;
  if (wid >= M_TOT) return;
  int s, e;
  if (wid < N_SUP) { s = spS[2 * wid]; e = spS[2 * wid + 1]; }
  else             { int w = wid - N_SUP; s = spQ[2 * w]; e = spQ[2 * w + 1]; }
  int len = e - s;
  float inv = 1.0f / (float)len;

  float acc0[3][4], accr[3][4];
  const ushort* Pr = PQR + (size_t)s * NG;
  const ushort* Qr = PQR + (size_t)(e - 1) * NG + 768;
#pragma unroll
  for (int c = 0; c < 3; ++c) {
    int h = c * 256 + lane * 4;
    ushort4 p = *(const ushort4*)(Pr + h);
    ushort4 q = *(const ushort4*)(Qr + h);
    acc0[c][0] = bf2f(p.x) + bf2f(q.x);
    acc0[c][1] = bf2f(p.y) + bf2f(q.y);
    acc0[c][2] = bf2f(p.z) + bf2f(q.z);
    acc0[c][3] = bf2f(p.w) + bf2f(q.w);
    accr[c][0] = accr[c][1] = accr[c][2] = accr[c][3] = 0.f;
  }
  for (int r = s; r < e; ++r) {
    const ushort* Rr = PQR + (size_t)r * NG + 1536;
#pragma unroll
    for (int c = 0; c < 3; ++c) {
      int h = c * 256 + lane * 4;
      ushort4 rv = *(const ushort4*)(Rr + h);
      accr[c][0] += bf2f(rv.x); accr[c][1] += bf2f(rv.y);
      accr[c][2] += bf2f(rv.z); accr[c][3] += bf2f(rv.w);
    }
  }
  ushort* er = emb + (size_t)wid * H_DIM;
#pragma unroll
  for (int c = 0; c < 3; ++c) {
    int h = c * 256 + lane * 4;
    float4 bv = *(const float4*)(bias + h);
    ushort4 o;
    o.x = f2bf(gelu_f(acc0[c][0] + accr[c][0] * inv + bv.x));
    o.y = f2bf(gelu_f(acc0[c][1] + accr[c][1] * inv + bv.y));
    o.z = f2bf(gelu_f(acc0[c][2] + accr[c][2] * inv + bv.z));
    o.w = f2bf(gelu_f(acc0[c][3] + accr[c][3] * inv + bv.w));
    *(ushort4*)(er + h) = o;
  }
}

// ---------------- proto accumulation: LDS-local segment sums + atomics ----------------
__global__ void proto_accum(const ushort* __restrict__ supEmb, const int* __restrict__ labels,
                            float* __restrict__ pSum, float* __restrict__ pCnt) {
  __shared__ float ls[C_CLS * H_DIM];
  __shared__ int lc[C_CLS];
  int t = threadIdx.x;
  for (int i = t; i < C_CLS * H_DIM; i += 256) ls[i] = 0.f;
  if (t < C_CLS) lc[t] = 0;
  __syncthreads();
  int base = blockIdx.x * 128;
  for (int si = 0; si < 128; ++si) {
    int sp = base + si;
    int lab = labels[sp];
    const ushort* er = supEmb + (size_t)sp * H_DIM;
#pragma unroll
    for (int j = 0; j < 3; ++j) {
      int c = t + j * 256;
      ls[lab * H_DIM + c] += bf2f(er[c]);
    }
    if (t == 0) lc[lab]++;
  }
  __syncthreads();
  for (int i = t; i < C_CLS * H_DIM; i += 256) atomicAdd(&pSum[i], ls[i]);
  if (t < C_CLS) atomicAdd(&pCnt[t], (float)lc[t]);
}

// ---------------- proto normalize (1 block) ----------------
__global__ void proto_norm(const float* __restrict__ pSum, const float* __restrict__ pCnt,
                           float* __restrict__ pN) {
  __shared__ float red[4];
  int t = threadIdx.x, lane = t & 63, wave = t >> 6;
  for (int c = 0; c < C_CLS; ++c) {
    float cnt = pCnt[c];
    float x[3];
#pragma unroll
    for (int j = 0; j < 3; ++j) {
      int h = t + j * 256;
      float v;
      if (cnt > 0.5f) v = pSum[c * H_DIM + h] / cnt;
      else {
        float gs = 0.f;
        for (int cc = 0; cc < C_CLS; ++cc) gs += pSum[cc * H_DIM + h];
        v = gs / (float)N_SUP;
      }
      x[j] = v;
    }
    float ss = x[0] * x[0] + x[1] * x[1] + x[2] * x[2];
#pragma unroll
    for (int o = 32; o; o >>= 1) ss += __shfl_xor(ss, o);
    if (lane == 0) red[wave] = ss;
    __syncthreads();
    float tot = red[0] + red[1] + red[2] + red[3];
    float inv = 1.0f / fmaxf(sqrtf(tot), 1e-12f);
#pragma unroll
    for (int j = 0; j < 3; ++j) pN[c * H_DIM + t + j * 256] = x[j] * inv;
    __syncthreads();
  }
}

// ---------------- query sim: one wave per query row ----------------
__global__ void sim_kernel(const ushort* __restrict__ emb, const float* __restrict__ pN,
                           float* __restrict__ out) {
  __shared__ float lp[C_CLS * H_DIM];
  int t = threadIdx.x;
  for (int i = t; i < C_CLS * H_DIM; i += 256) lp[i] = pN[i];
  __syncthreads();
  int lane = t & 63, wave = t >> 6;
  for (int row = blockIdx.x * 4 + wave; row < Q_QRY; row += gridDim.x * 4) {
    const ushort* qr = emb + (size_t)(N_SUP + row) * H_DIM;
    float dot[C_CLS] = {0, 0, 0, 0, 0, 0, 0, 0, 0, 0};
    float sq = 0.f;
#pragma unroll
    for (int j = 0; j < 12; ++j) {
      float v = bf2f(qr[lane + 64 * j]);
      sq += v * v;
#pragma unroll
      for (int p = 0; p < C_CLS; ++p) dot[p] += v * lp[p * H_DIM + lane + 64 * j];
    }
#pragma unroll
    for (int o = 32; o; o >>= 1) {
      sq += __shfl_xor(sq, o);
#pragma unroll
      for (int p = 0; p < C_CLS; ++p) dot[p] += __shfl_xor(dot[p], o);
    }
    if (lane == 0) {
      float inv = 1.0f / fmaxf(sqrtf(sq), 1e-12f);
      float* o = out + (size_t)row * (C_CLS + 1);
      o[0] = dot[0] * inv; o[1] = dot[1] * inv; o[2] = dot[2] * inv;
      o[3] = dot[3] * inv; o[4] = dot[4] * inv; o[5] = dot[5] * inv;
      o[6] = dot[6] * inv; o[7] = dot[7] * inv; o[8] = dot[8] * inv;
      o[9] = dot[9] * inv; o[10] = 0.5f;
    }
  }
}

extern "C" void kernel_launch(void* const* d_in, const int* in_sizes, int n_in,
                              void* d_out, int out_size, void* d_ws, size_t ws_size,
                              hipStream_t stream) {
  const float* token_emb = (const float*)d_in[0];
  const int*   spansS    = (const int*)d_in[1];
  const int*   labels    = (const int*)d_in[2];
  const int*   spansQ    = (const int*)d_in[3];
  const float* W         = (const float*)d_in[4];
  const float* b         = (const float*)d_in[5];
  float* out = (float*)d_out;

  char* ws = (char*)d_ws;
  size_t pqrB = (size_t)M_TOT * NG * 2;        // 301,989,888
  size_t embB = (size_t)M_TOT * H_DIM * 2;     // 100,663,296
  size_t wtB  = (size_t)NG * KG * 2;           //   3,538,944
  ushort* PQR  = (ushort*)ws;
  ushort* tebf = (ushort*)(ws + pqrB);         // te_bf16; dead after gemm8
  ushort* emb  = tebf;                          // emb aliases tebf (sequential lifetimes)
  ushort* Bt   = (ushort*)(ws + pqrB + embB);
  float*  pSum = (float*)(ws + pqrB + embB + wtB);
  float*  pCnt = pSum + C_CLS * H_DIM;
  float*  pN   = pCnt + 64;

  hipMemsetAsync(pSum, 0, (C_CLS * H_DIM + 64) * sizeof(float), stream);
  cvt_kernel<<<24576, 256, 0, stream>>>(token_emb, tebf);
  wt2_kernel<<<6912, 256, 0, stream>>>(W, Bt);
  gemm8<<<2304, 512, 0, stream>>>(tebf, Bt, PQR);
  combine_kernel<<<16384, 256, 0, stream>>>(PQR, spansS, spansQ, b, emb);
  proto_accum<<<N_SUP / 128, 256, 0, stream>>>(emb, labels, pSum, pCnt);
  proto_norm<<<1, 256, 0, stream>>>(pSum, pCnt, pN);
  sim_kernel<<<512, 256, 0, stream>>>(emb, pN, out);
}